// Round 10
// baseline (4404.608 us; speedup 1.0000x reference)
//
#include <hip/hip_runtime.h>

// 3-layer LSTM, B=256, T=2048, H=128 — v9: NB=4 "lane-bijective" restructure.
// R9 falsified the launch-bounds/VGPR story: (NT,1) still 128 VGPR, same perf.
// gfx950 MFMA reads B from AGPR natively -> no shuttle ever existed. Real step
// budget (v8, per SIMD): VALU 1885cy (gates: 4 (unit,seq) pairs/lane x ~25
// insts, 10 quarter-rate transcendentals each) + MFMA 320cy + ~2100cy gaps.
// v9: 64 groups x 4 seqs x 3 layers = 192 blocks. Seqs sit in MFMA A-rows
// {0,4,8,12} so lane(c,p) holds its single valid C element in acc[q][0]
// (row=4p, col=c): gate code runs ONCE per lane (4x fewer instructions
// issued, not masked). MFMA per block-step unchanged (75% tile waste, but
// MFMA was only 320cy/SIMD — not binding). Extra cuts in the new gate path:
//  - bias (and L0's x*w0) folded into MFMA C-init
//  - proj chained into the same accumulator (8-deep, 4 indep chains)
//  - weights/biases pre-scaled by -log2e (g-gate: -2log2e) at convert time:
//    sigma = rcp(1+exp2(z)), tanh = fma(2, rcp(1+exp2(z)), -1)
// Predict: dur 1100-1700us, VALUBusy(global) 20-30%, absmax <= 1.6e-3.

#define HDIM 128
#define TDIM 2048
#define NB 4        // sequences per group (A-rows 0,4,8,12)
#define NG 64       // groups
#define CH 16       // chunk length (timesteps)
#define NCH 128     // chunks per sequence
#define NT 512      // 8 waves
#define SLICE 2048  // fp16 per h slice (16 rows x 128)

typedef _Float16 half8_t __attribute__((ext_vector_type(8)));
typedef float f32x4 __attribute__((ext_vector_type(4)));
typedef int int4v __attribute__((ext_vector_type(4)));

__device__ __forceinline__ f32x4 mfma16(half8_t a, half8_t b, f32x4 c) {
    return __builtin_amdgcn_mfma_f32_16x16x32_f16(a, b, c, 0, 0, 0);
}

// Workgroup barrier WITHOUT vmcnt(0) drain: LDS visibility only.
__device__ __forceinline__ void fast_barrier() {
    asm volatile("s_waitcnt lgkmcnt(0)\n\ts_barrier" ::: "memory");
}

__device__ __forceinline__ float rcpf(float x) { return __builtin_amdgcn_rcpf(x); }
__device__ __forceinline__ float ex2(float x)  { return __builtin_amdgcn_exp2f(x); }

#define NL2E  -1.4426950408889634f   // -log2(e)
#define N2L2E -2.8853900817779268f   // -2*log2(e)

// One-time fp32 -> fp16 weight conversion + gate-wise log2e prescale + flag
// zeroing. Segments of 65536: [Whh0,Wih1,Whh1,Wih2,Whh2]; every segment is a
// [512][128] gate-row matrix; gate = row>>7. i,f,o rows * -log2e; g rows *
// -2log2e (sigma/tanh consume exp2 of the NEGATED scaled preactivation).
__global__ __launch_bounds__(256)
void convert_w(const float* __restrict__ Whh0, const float* __restrict__ Wih1,
               const float* __restrict__ Whh1, const float* __restrict__ Wih2,
               const float* __restrict__ Whh2, _Float16* __restrict__ dst,
               int* __restrict__ flags) {
    int i = blockIdx.x * 256 + threadIdx.x;
    if (i < 2 * NG * NCH) flags[i] = 0;
    int seg = i >> 16, off = i & 65535;
    const float* s = (seg == 0) ? Whh0 : (seg == 1) ? Wih1 : (seg == 2) ? Whh1
                   : (seg == 3) ? Wih2 : Whh2;
    int gate = off >> 14;               // off>>7 = row (0..511); row>>7 = gate
    float sc = (gate == 2) ? N2L2E : NL2E;
    dst[i] = (_Float16)(s[off] * sc);
}

__global__ __launch_bounds__(NT, 1)
void lstm3_pipe(const float* __restrict__ x,   const float* __restrict__ Wih0,
                const float* __restrict__ bih0, const float* __restrict__ bhh0,
                const float* __restrict__ bih1, const float* __restrict__ bhh1,
                const float* __restrict__ bih2, const float* __restrict__ bhh2,
                const float* __restrict__ fc1w, const float* __restrict__ fc1b,
                const float* __restrict__ fc2w, const float* __restrict__ fc2b,
                float* __restrict__ out,
                _Float16* __restrict__ hbuf, const _Float16* __restrict__ wbuf,
                int* __restrict__ flags)
{
    // h windows: 16 slices of 16 rows x 128 units; seqs at rows {0,4,8,12},
    // other rows garbage (only pollute unread C rows). Swizzle: row r stores
    // unit u at column u ^ (8*(r&7)).
    __shared__ __align__(16) _Float16 hown[CH * SLICE];  // 64 KB
    __shared__ __align__(16) _Float16 hst [CH * SLICE];  // 64 KB
    __shared__ float x_s[CH][NB];                        // layer0 input
    __shared__ float z_s[NB][64];                        // FC tail
    __shared__ float hfin[NB][HDIM];                     // de-swizzled hT

    const int tid = threadIdx.x;
    const int ln = tid & 63, wv = tid >> 6;   // wave j owns units [16j,16j+16)
    const int c = ln & 15, p = ln >> 4;       // unit-col / SEQ index (0..3)
    const int L = blockIdx.x >> 6;            // layer 0..2 (layer0 = bids 0..63)
    const int g = blockIdx.x & 63;            // seq group

    // ---- resident weight fragments (arch VGPR or AGPR — MFMA reads both)
    const _Float16* whh = wbuf + (size_t)((L == 0) ? 0 : (L == 1) ? 2 : 4) * 65536;
    const _Float16* wih = wbuf + (size_t)((L == 1) ? 1 : 3) * 65536;  // L0: unused
    half8_t whh_f[4][4], wih_f[4][4];
#pragma unroll
    for (int q = 0; q < 4; ++q)
#pragma unroll
        for (int m = 0; m < 4; ++m) {
            whh_f[q][m] = *(const half8_t*)(whh + (size_t)(q*HDIM + wv*16 + c)*HDIM + m*32 + p*8);
            if (L > 0)
                wih_f[q][m] = *(const half8_t*)(wih + (size_t)(q*HDIM + wv*16 + c)*HDIM + m*32 + p*8);
        }

    const float* bihL = (L == 0) ? bih0 : (L == 1) ? bih1 : bih2;
    const float* bhhL = (L == 0) ? bhh0 : (L == 1) ? bhh1 : bhh2;
    const int u = wv * 16 + c;                // this lane's unit
    float bias[4], w0[4];
#pragma unroll
    for (int q = 0; q < 4; ++q) {
        float sc = (q == 2) ? N2L2E : NL2E;   // match convert_w prescale
        bias[q] = (bihL[q*HDIM + u] + bhhL[q*HDIM + u]) * sc;
        w0[q] = (L == 0) ? Wih0[q*HDIM + u] * sc : 0.0f;
    }

    // A-frag read offsets (row = c, k = m*32 + p*8), swizzled by row&7
    int roff[4];
#pragma unroll
    for (int m = 0; m < 4; ++m)
        roff[m] = c*HDIM + ((32*m + 8*p) ^ (8*(c & 7)));
    // h write: seq p -> row 4p, unit u, swizzle 8*((4p)&7) = 32*(p&1)
    const int woff = (4*p)*HDIM + (u ^ (32*(p & 1)));

    // zero both windows once (h(-1)=0 in slice 15; garbage rows made benign)
    { int* ph = (int*)hown; int* ps = (int*)hst;
      for (int i = tid; i < CH*SLICE/2; i += NT) { ph[i] = 0; ps[i] = 0; } }
    float cc = 0.f;
    __syncthreads();

    int* fprod = flags + (L*NG + g)*NCH;          // set by this block (L<2)
    int* fcons = flags + ((L-1)*NG + g)*NCH;      // waited on (L>0)
    const float* xb = x + (size_t)(g*NB)*TDIM;

#pragma unroll 1
    for (int s = 0; s < NCH; ++s) {
        // compact 16 KB chunk slot: [tt][s4][u8] int4 = 8 units, swizzled
        _Float16* gch = hbuf + ((size_t)(g*NCH + s) << 13);

        if (L == 0) {
            if (tid < CH*NB)
                x_s[tid >> 2][tid & 3] = xb[(size_t)(tid & 3)*TDIM + s*CH + (tid >> 2)];
        } else {
            if (tid == 0) {
                while (__hip_atomic_load(fcons + s, __ATOMIC_ACQUIRE,
                                         __HIP_MEMORY_SCOPE_AGENT) == 0)
                    __builtin_amdgcn_s_sleep(8);
            }
            __syncthreads();
#pragma unroll
            for (int k2 = 0; k2 < 2; ++k2) {
                int e = k2*NT + tid;                     // 0..1023 int4s
                int tt_ = e >> 6, rem = e & 63, s4 = rem >> 4, u8 = (rem & 15)*8;
                int lo = tt_*SLICE + s4*4*HDIM + (u8 ^ (32*(s4 & 1)));
                *(int4v*)(hst + lo) = ((const int4v*)gch)[e];
            }
        }
        fast_barrier();   // x_s / hst visible

#pragma unroll 1
        for (int tt = 0; tt < CH; ++tt) {
            const int tp = (tt + CH - 1) & 15;
            const _Float16* rsl = hown + tp*SLICE;
            half8_t A0 = *(const half8_t*)(rsl + roff[0]);
            half8_t A1 = *(const half8_t*)(rsl + roff[1]);
            half8_t A2 = *(const half8_t*)(rsl + roff[2]);
            half8_t A3 = *(const half8_t*)(rsl + roff[3]);

            // C-init = bias (+ x*w0 for L0); proj chained in, then rec:
            // 4 independent 8-deep chains (issue-bound, not latency-bound)
            f32x4 acc[4];
            if (L == 0) {
                float xv = x_s[tt][p];
#pragma unroll
                for (int q = 0; q < 4; ++q) {
                    float z0 = fmaf(xv, w0[q], bias[q]);
                    acc[q] = (f32x4){z0, z0, z0, z0};
                }
            } else {
#pragma unroll
                for (int q = 0; q < 4; ++q)
                    acc[q] = (f32x4){bias[q], bias[q], bias[q], bias[q]};
                const _Float16* psl = hst + tt*SLICE;
                half8_t P0 = *(const half8_t*)(psl + roff[0]);
                half8_t P1 = *(const half8_t*)(psl + roff[1]);
                half8_t P2 = *(const half8_t*)(psl + roff[2]);
                half8_t P3 = *(const half8_t*)(psl + roff[3]);
#pragma unroll
                for (int q = 0; q < 4; ++q) {
                    acc[q] = mfma16(P0, wih_f[q][0], acc[q]);
                    acc[q] = mfma16(P1, wih_f[q][1], acc[q]);
                    acc[q] = mfma16(P2, wih_f[q][2], acc[q]);
                    acc[q] = mfma16(P3, wih_f[q][3], acc[q]);
                }
            }
#pragma unroll
            for (int q = 0; q < 4; ++q) {
                acc[q] = mfma16(A0, whh_f[q][0], acc[q]);
                acc[q] = mfma16(A1, whh_f[q][1], acc[q]);
                acc[q] = mfma16(A2, whh_f[q][2], acc[q]);
                acc[q] = mfma16(A3, whh_f[q][3], acc[q]);
            }

            // ---- gates: ONE (unit,seq) pair per lane (row 4p, col c) ----
            // z already = -log2e * preact (g: -2log2e) incl. bias (+x*w0)
            float ai = rcpf(1.0f + ex2(acc[0][0]));
            float af = rcpf(1.0f + ex2(acc[1][0]));
            float tg = fmaf(2.0f, rcpf(1.0f + ex2(acc[2][0])), -1.0f);
            float ao = rcpf(1.0f + ex2(acc[3][0]));
            cc = fmaf(af, cc, ai * tg);
            float tc = fmaf(2.0f, rcpf(1.0f + ex2(cc * N2L2E)), -1.0f);
            hown[tt*SLICE + woff] = (_Float16)(ao * tc);

            fast_barrier();   // h(tt) visible for step tt+1
        }

        if (L < 2) {
            // publish compact chunk (plain stores -> L2), fence, release flag
#pragma unroll
            for (int k2 = 0; k2 < 2; ++k2) {
                int e = k2*NT + tid;
                int tt_ = e >> 6, rem = e & 63, s4 = rem >> 4, u8 = (rem & 15)*8;
                int lo = tt_*SLICE + s4*4*HDIM + (u8 ^ (32*(s4 & 1)));
                ((int4v*)gch)[e] = *(const int4v*)(hown + lo);
            }
            __threadfence();
            __syncthreads();
            if (tid == 0)
                __hip_atomic_store(fprod + s, 1, __ATOMIC_RELEASE,
                                   __HIP_MEMORY_SCOPE_AGENT);
        }
    }

    // ---- FC head (layer-2 blocks): hT = hown slice 15, rows {0,4,8,12} ----
    if (L == 2) {
        __syncthreads();
        for (int i = tid; i < NB*HDIM; i += NT) {
            int seq = i >> 7, uu = i & 127;
            hfin[seq][uu] = (float)hown[15*SLICE + seq*4*HDIM + (uu ^ (32*(seq & 1)))];
        }
        __syncthreads();
        if (tid < NB*64) {
            int seq = tid >> 6, un = tid & 63;
            const float4* w4 = (const float4*)(fc1w + un*HDIM);
            const float4* h4 = (const float4*)hfin[seq];
            float sacc = fc1b[un];
#pragma unroll
            for (int k2 = 0; k2 < 32; ++k2) {
                float4 a = w4[k2], bb = h4[k2];
                sacc += a.x*bb.x + a.y*bb.y + a.z*bb.z + a.w*bb.w;
            }
            z_s[seq][un] = fmaxf(sacc, 0.0f);
        }
        __syncthreads();
        if (tid < NB*5) {
            int seq = tid / 5, o = tid - seq*5;
            const float* w = fc2w + o*64;
            float sacc = fc2b[o];
#pragma unroll
            for (int k2 = 0; k2 < 64; ++k2) sacc += w[k2] * z_s[seq][k2];
            out[(size_t)(g*NB + seq)*5 + o] = sacc;
        }
    }
}

extern "C" void kernel_launch(void* const* d_in, const int* in_sizes, int n_in,
                              void* d_out, int out_size, void* d_ws, size_t ws_size,
                              hipStream_t stream) {
    (void)in_sizes; (void)n_in; (void)out_size; (void)ws_size;
    const float* x    = (const float*)d_in[0];
    const float* Wih0 = (const float*)d_in[1];
    const float* Whh0 = (const float*)d_in[2];
    const float* bih0 = (const float*)d_in[3];
    const float* bhh0 = (const float*)d_in[4];
    const float* Wih1 = (const float*)d_in[5];
    const float* Whh1 = (const float*)d_in[6];
    const float* bih1 = (const float*)d_in[7];
    const float* bhh1 = (const float*)d_in[8];
    const float* Wih2 = (const float*)d_in[9];
    const float* Whh2 = (const float*)d_in[10];
    const float* bih2 = (const float*)d_in[11];
    const float* bhh2 = (const float*)d_in[12];
    const float* fc1w = (const float*)d_in[13];
    const float* fc1b = (const float*)d_in[14];
    const float* fc2w = (const float*)d_in[15];
    const float* fc2b = (const float*)d_in[16];
    float* out = (float*)d_out;

    _Float16* hbuf = (_Float16*)d_ws;                    // 128 MB: 64*128 x 16KB slots
    _Float16* wbuf = hbuf + (size_t)67108864;            // fp16 weights (640 KB)
    int* flags = (int*)(wbuf + (size_t)5*65536);         // 2*64*128 ints (64 KB)

    hipLaunchKernelGGL(convert_w, dim3(1280), dim3(256), 0, stream,
                       Whh0, Wih1, Whh1, Wih2, Whh2, wbuf, flags);
    hipLaunchKernelGGL(lstm3_pipe, dim3(3*NG), dim3(NT), 0, stream,
                       x, Wih0, bih0, bhh0, bih1, bhh1, bih2, bhh2,
                       fc1w, fc1b, fc2w, fc2b, out, hbuf, wbuf, flags);
}